// Round 13
// baseline (103.454 us; speedup 1.0000x reference)
//
#include <hip/hip_runtime.h>

#define SLEN 8192
#define DIN  512

typedef short bf16x8 __attribute__((ext_vector_type(8)));
typedef float f32x4  __attribute__((ext_vector_type(4)));
typedef float f32x16 __attribute__((ext_vector_type(16)));
typedef unsigned int u32x4 __attribute__((ext_vector_type(4)));
typedef unsigned int u32x2 __attribute__((ext_vector_type(2)));

__device__ __forceinline__ unsigned short f2bf(float f) {
  unsigned int u = __float_as_uint(f);
  u += 0x7FFFu + ((u >> 16) & 1u);           // RNE
  return (unsigned short)(u >> 16);
}
__device__ __forceinline__ float bf2f(unsigned short h) {
  return __uint_as_float(((unsigned int)h) << 16);
}
__device__ __forceinline__ unsigned int cvtpk(float lo, float hi) {
  unsigned int r;
  asm volatile("v_cvt_pk_bf16_f32 %0, %1, %2" : "=v"(r) : "v"(lo), "v"(hi));
  return r;
}

#define MFMA16(a, b, c) __builtin_amdgcn_mfma_f32_16x16x32_bf16((a), (b), (c), 0, 0, 0)
#define MFMA32(a, b, c) __builtin_amdgcn_mfma_f32_32x32x16_bf16((a), (b), (c), 0, 0, 0)

// XOR swizzle for [row][128B] LDS tiles (read side; write side = pre-swizzled global src)
__device__ __forceinline__ int SW(int row, int off) {
  return row * 128 + (off ^ ((row & 7) << 4));
}

// ---------------- A: split x (f32) -> xh, xl (bf16), pure BW ----------------
__global__ __launch_bounds__(256) void k_splitx(const float* __restrict__ x,
                                                unsigned short* __restrict__ xh,
                                                unsigned short* __restrict__ xl) {
  int i = blockIdx.x * 256 + threadIdx.x;    // float4 index, 1048576 total
  float4 v = reinterpret_cast<const float4*>(x)[i];
  float vv[4] = {v.x, v.y, v.z, v.w};
  unsigned long long ph = 0ull, pl = 0ull;
#pragma unroll
  for (int j = 0; j < 4; ++j) {
    unsigned short h = f2bf(vv[j]);
    unsigned short l = f2bf(vv[j] - bf2f(h));
    ph |= ((unsigned long long)h) << (16 * j);
    pl |= ((unsigned long long)l) << (16 * j);
  }
  reinterpret_cast<unsigned long long*>(xh)[i] = ph;
  reinterpret_cast<unsigned long long*>(xl)[i] = pl;
}

// ------- B: split + transpose W -> Wt[n][k], n: 0-63 Q(scaled), 64-127 K, 128-191 V -------
__global__ __launch_bounds__(256) void k_splitw(const float* __restrict__ Wq,
                                                const float* __restrict__ Wk,
                                                const float* __restrict__ Wv,
                                                unsigned short* __restrict__ Wth,
                                                unsigned short* __restrict__ Wtl) {
  int idx = blockIdx.x * 256 + threadIdx.x;  // n*512 + k, 98304 total
  int n = idx >> 9, k = idx & 511;
  float w;
  if (n < 64)       w = Wq[k * 64 + n] * 0.18033688011112042f;  // log2(e)/8 folded in
  else if (n < 128) w = Wk[k * 64 + (n - 64)];
  else              w = Wv[k * 64 + (n - 128)];
  unsigned short h = f2bf(w);
  Wth[idx] = h;
  Wtl[idx] = f2bf(w - bf2f(h));
}

// ---------------- C: QKV = x @ [Wq|Wk|Wv], bf16 hi/lo inputs, 16-row m-tiles ----------------
__global__ __launch_bounds__(256) void k_qkv(const unsigned short* __restrict__ xh,
                                             const unsigned short* __restrict__ xl,
                                             const unsigned short* __restrict__ Wth,
                                             const unsigned short* __restrict__ Wtl,
                                             unsigned short* __restrict__ Qh,
                                             unsigned short* __restrict__ Ql,
                                             unsigned short* __restrict__ Kh,
                                             unsigned short* __restrict__ Kl,
                                             unsigned short* __restrict__ Vt) {
  const int tid = threadIdx.x;
  const int wave = tid >> 6, lane = tid & 63;
  const int c = lane & 15, g = lane >> 4;
  const int mbase = blockIdx.x * 16;              // 512 m-tiles of 16 rows
  const int nt0 = wave * 3;                       // each wave: 3 of 12 n-tiles

  const int rowA = mbase + c;                     // all waves share rows (L1 broadcast)
  f32x4 acc[3];
  for (int j = 0; j < 3; ++j) acc[j] = (f32x4){0.f, 0.f, 0.f, 0.f};

  for (int k0 = 0; k0 < DIN; k0 += 32) {
    bf16x8 ah = *reinterpret_cast<const bf16x8*>(&xh[(size_t)rowA * DIN + k0 + g * 8]);
    bf16x8 al = *reinterpret_cast<const bf16x8*>(&xl[(size_t)rowA * DIN + k0 + g * 8]);
#pragma unroll
    for (int j = 0; j < 3; ++j) {
      int ncol = (nt0 + j) * 16 + c;
      bf16x8 bh = *reinterpret_cast<const bf16x8*>(&Wth[ncol * DIN + k0 + g * 8]);
      bf16x8 bl = *reinterpret_cast<const bf16x8*>(&Wtl[ncol * DIN + k0 + g * 8]);
      acc[j] = MFMA16(ah, bh, acc[j]);
      acc[j] = MFMA16(ah, bl, acc[j]);
      acc[j] = MFMA16(al, bh, acc[j]);
    }
  }
  // C layout: col=lane&15, row=(lane>>4)*4+r  (16-row tile)
#pragma unroll
  for (int j = 0; j < 3; ++j) {
    int nt = nt0 + j;
    if (nt < 8) {
#pragma unroll
      for (int r = 0; r < 4; ++r) {
        int Rrow = mbase + g * 4 + r;
        float v = acc[j][r];
        unsigned short h = f2bf(v);
        unsigned short lo = f2bf(v - bf2f(h));
        if (nt < 4) {
          Qh[Rrow * 64 + nt * 16 + c] = h;
          Ql[Rrow * 64 + nt * 16 + c] = lo;
        } else {
          Kh[Rrow * 64 + (nt - 4) * 16 + c] = h;
          Kl[Rrow * 64 + (nt - 4) * 16 + c] = lo;
        }
      }
    } else {
      int np = nt * 16 + c - 128;
      int Rbase = mbase + g * 4;
      u32x2 pk;
      pk.x = cvtpk(acc[j][0], acc[j][1]);
      pk.y = cvtpk(acc[j][2], acc[j][3]);
      *reinterpret_cast<u32x2*>(&Vt[(size_t)np * SLEN + Rbase]) = pk;  // V^T [64][8192]
    }
  }
}

// ---------------- D: flash attention, swapped 32x32, DMA double-buffer staging ----------------
template <int NS>
__global__ __launch_bounds__(256, 2) void k_flash(const unsigned short* __restrict__ Qh,
                                                  const unsigned short* __restrict__ Ql,
                                                  const unsigned short* __restrict__ Kh,
                                                  const unsigned short* __restrict__ Kl,
                                                  const unsigned short* __restrict__ Vt,
                                                  unsigned short* __restrict__ pOn,
                                                  float* __restrict__ pML) {
  constexpr int KIT = 128 / NS;   // 64-key tiles per split
  __shared__ __align__(16) unsigned char smem[2 * 24576];   // dbuf {KH,KL,VT}
  const int tid = threadIdx.x;
  const int wave = tid >> 6, lane = tid & 63;
  const int q32 = lane & 31, hi = lane >> 5;
  const int qtile = blockIdx.x;   // 32 q-tiles of 256
  const int ks = blockIdx.y;

  // Q B-fragments: B[k=hi*8+j][col=q32], per (qs, kk): bf16x8 of own q-row
  int qrow[2];
  bf16x8 qfh[2][4], qfl[2][4];
#pragma unroll
  for (int qs = 0; qs < 2; ++qs) {
    qrow[qs] = qtile * 256 + wave * 64 + qs * 32 + q32;
#pragma unroll
    for (int kk = 0; kk < 4; ++kk) {
      qfh[qs][kk] = *reinterpret_cast<const bf16x8*>(&Qh[qrow[qs] * 64 + kk * 16 + hi * 8]);
      qfl[qs][kk] = *reinterpret_cast<const bf16x8*>(&Ql[qrow[qs] * 64 + kk * 16 + hi * 8]);
    }
  }
  bf16x8 ones8;
#pragma unroll
  for (int j = 0; j < 8; ++j) ones8[j] = (short)0x3F80;

  f32x16 o[2][2];
#pragma unroll
  for (int qs = 0; qs < 2; ++qs)
#pragma unroll
    for (int db = 0; db < 2; ++db)
#pragma unroll
      for (int r = 0; r < 16; ++r) o[qs][db][r] = 0.f;
  float m_run[2] = {-1e30f, -1e30f};
  float l_run[2] = {0.f, 0.f};

  // DMA staging: wave w covers chunks [w*6, w*6+6) of 24 x 1KB; lane lays its 16B at
  // base + lane*16 (HW). Global source col pre-swizzled so LDS[row][seg] = G[row][seg^(row&7)],
  // matching SW() on the read side (rule 21: linear dest + inverse-swizzled source).
  const int r8 = lane >> 3;
  const int ce = ((lane & 7) ^ r8) * 8;          // source col in elems (8 bf16 = 16B)
  auto STAGE = [&](int it, int bo) {
    const int kb = ks * (SLEN / NS) + it * 64;
#pragma unroll
    for (int u = 0; u < 6; ++u) {
      int ch = wave * 6 + u;
      int arr = ch >> 3;
      int row = (ch & 7) * 8 + r8;
      const unsigned short* src;
      if (arr == 0)      src = &Kh[(kb + row) * 64 + ce];
      else if (arr == 1) src = &Kl[(kb + row) * 64 + ce];
      else               src = &Vt[(size_t)row * SLEN + kb + ce];
      __builtin_amdgcn_global_load_lds(
          (const __attribute__((address_space(1))) unsigned int*)src,
          (__attribute__((address_space(3))) unsigned int*)(smem + bo + ch * 1024),
          16, 0, 0);
    }
  };

  int boff = 0;
  STAGE(0, 0);
  __syncthreads();                                // vmcnt(0): first tile landed

  for (int it = 0; it < KIT; ++it) {
    if (it + 1 < KIT) STAGE(it + 1, boff ^ 24576);   // next tile flies during compute
    unsigned char* KH = smem + boff;
    unsigned char* KL = KH + 8192;
    unsigned char* VT = KH + 16384;

#pragma unroll
    for (int s = 0; s < 2; ++s) {          // two 32-key subtiles
      bf16x8 kfh[4], kfl[4], vf[2][2];
#pragma unroll
      for (int kk = 0; kk < 4; ++kk) {
        kfh[kk] = *reinterpret_cast<const bf16x8*>(&KH[SW(32 * s + q32, 32 * kk + 16 * hi)]);
        kfl[kk] = *reinterpret_cast<const bf16x8*>(&KL[SW(32 * s + q32, 32 * kk + 16 * hi)]);
      }
#pragma unroll
      for (int db = 0; db < 2; ++db)
#pragma unroll
        for (int ch = 0; ch < 2; ++ch)
          vf[db][ch] = *reinterpret_cast<const bf16x8*>(&VT[SW(32 * db + q32, 64 * s + 32 * ch + 16 * hi)]);

#pragma unroll
      for (int qs = 0; qs < 2; ++qs) {
        // S^T = K·Q^T: D[k=crow(r,hi)][q=q32]
        f32x16 S;
#pragma unroll
        for (int r = 0; r < 16; ++r) S[r] = 0.f;
        __builtin_amdgcn_s_setprio(1);
#pragma unroll
        for (int kk = 0; kk < 4; ++kk) {
          S = MFMA32(kfh[kk], qfh[qs][kk], S);
          S = MFMA32(kfh[kk], qfl[qs][kk], S);
          S = MFMA32(kfl[kk], qfh[qs][kk], S);
        }
        __builtin_amdgcn_s_setprio(0);

        // lane-local row max (own 16 k) + cross-half combine
        float pm = S[0];
#pragma unroll
        for (int r = 1; r < 16; ++r) pm = fmaxf(pm, S[r]);
        pm = fmaxf(pm, __shfl_xor(pm, 32));
        if (!__all(pm - m_run[qs] <= 8.0f)) {   // defer-max (T13)
          float mnew = fmaxf(m_run[qs], pm);
          float alpha = exp2f(m_run[qs] - mnew);
#pragma unroll
          for (int db = 0; db < 2; ++db)
#pragma unroll
            for (int r = 0; r < 16; ++r) o[qs][db][r] *= alpha;
          l_run[qs] *= alpha;
          m_run[qs] = mnew;
        }
        float p[16];
#pragma unroll
        for (int r = 0; r < 16; ++r) p[r] = exp2f(S[r] - m_run[qs]);
        unsigned int W[8];
#pragma unroll
        for (int i = 0; i < 8; ++i) W[i] = cvtpk(p[2 * i], p[2 * i + 1]);
        // redistribute k-halves across lane halves -> PV B-fragments (T12)
        asm volatile("v_permlane32_swap_b32 %0, %1" : "+v"(W[0]), "+v"(W[2]));
        asm volatile("v_permlane32_swap_b32 %0, %1" : "+v"(W[1]), "+v"(W[3]));
        asm volatile("v_permlane32_swap_b32 %0, %1" : "+v"(W[4]), "+v"(W[6]));
        asm volatile("v_permlane32_swap_b32 %0, %1" : "+v"(W[5]), "+v"(W[7]));
        u32x4 pw0 = {W[0], W[1], W[2], W[3]};
        u32x4 pw1 = {W[4], W[5], W[6], W[7]};
        bf16x8 pb0 = *reinterpret_cast<bf16x8*>(&pw0);
        bf16x8 pb1 = *reinterpret_cast<bf16x8*>(&pw1);

        __builtin_amdgcn_s_setprio(1);
        f32x16 rs;
#pragma unroll
        for (int r = 0; r < 16; ++r) rs[r] = 0.f;
        rs = MFMA32(ones8, pb0, rs);            // rowsum[q] in every row
        rs = MFMA32(ones8, pb1, rs);
        // O^T[d][q] += V^T·P^T
        o[qs][0] = MFMA32(vf[0][0], pb0, o[qs][0]);
        o[qs][0] = MFMA32(vf[0][1], pb1, o[qs][0]);
        o[qs][1] = MFMA32(vf[1][0], pb0, o[qs][1]);
        o[qs][1] = MFMA32(vf[1][1], pb1, o[qs][1]);
        __builtin_amdgcn_s_setprio(0);
        l_run[qs] += rs[0];
      }
    }
    __syncthreads();     // vmcnt(0)+lgkmcnt(0)+barrier: next tile landed, cur buffer free
    boff ^= 24576;
  }

  // epilogue: normalized bf16 partials + (m,l)
#pragma unroll
  for (int qs = 0; qs < 2; ++qs) {
    float inv = 1.0f / l_run[qs];
#pragma unroll
    for (int db = 0; db < 2; ++db)
#pragma unroll
      for (int i = 0; i < 8; ++i) {
        unsigned int w = cvtpk(o[qs][db][2 * i] * inv, o[qs][db][2 * i + 1] * inv);
        int d = 2 * (i & 1) + 8 * (i >> 1) + 4 * hi + 32 * db;
        *reinterpret_cast<unsigned int*>(&pOn[((size_t)ks * SLEN + qrow[qs]) * 64 + d]) = w;
      }
    if (hi == 0) {
      pML[((size_t)ks * SLEN + qrow[qs]) * 2 + 0] = m_run[qs];
      pML[((size_t)ks * SLEN + qrow[qs]) * 2 + 1] = l_run[qs];
    }
  }
}

// ---------------- E: merge K-split partials (u32-pair vectorized) ----------------
template <int NS>
__global__ __launch_bounds__(256) void k_merge(const unsigned short* __restrict__ pOn,
                                               const float* __restrict__ pML,
                                               float* __restrict__ out) {
  int idx = blockIdx.x * 256 + threadIdx.x;  // 262144 u32-pairs
  int row = idx >> 5, dp = idx & 31;
  float ms[NS], ls[NS];
  float M = -1e30f;
#pragma unroll
  for (int s = 0; s < NS; ++s) {
    ms[s] = pML[((size_t)s * SLEN + row) * 2 + 0];
    ls[s] = pML[((size_t)s * SLEN + row) * 2 + 1];
    M = fmaxf(M, ms[s]);
  }
  float Wsum = 0.f, O0 = 0.f, O1 = 0.f;
  const unsigned int* pOn32 = reinterpret_cast<const unsigned int*>(pOn);
#pragma unroll
  for (int s = 0; s < NS; ++s) {
    float w = ls[s] * exp2f(ms[s] - M);
    unsigned int v = pOn32[((size_t)s * SLEN + row) * 32 + dp];
    O0 += w * bf2f((unsigned short)(v & 0xFFFF));
    O1 += w * bf2f((unsigned short)(v >> 16));
    Wsum += w;
  }
  float inv = 1.0f / Wsum;
  float2 res = {O0 * inv, O1 * inv};
  *reinterpret_cast<float2*>(&out[(size_t)row * 64 + dp * 2]) = res;
}

extern "C" void kernel_launch(void* const* d_in, const int* in_sizes, int n_in,
                              void* d_out, int out_size, void* d_ws, size_t ws_size,
                              hipStream_t stream) {
  const float* x  = (const float*)d_in[0];
  const float* Wq = (const float*)d_in[1];
  const float* Wk = (const float*)d_in[2];
  const float* Wv = (const float*)d_in[3];
  float* out = (float*)d_out;

  char* w = (char*)d_ws;
  const size_t QB = (size_t)SLEN * 64 * 2;       // 1,048,576 per buffer
  unsigned short* Qh = (unsigned short*)w;
  unsigned short* Ql = Qh + SLEN * 64;
  unsigned short* Kh = Ql + SLEN * 64;
  unsigned short* Kl = Kh + SLEN * 64;
  unsigned short* Vt = Kl + SLEN * 64;
  char* tail = w + 5 * QB;                       // 5,242,880

  // stage-1 overlay of tail: xh, xl, Wth, Wtl (17.2 MB) — dead once k_qkv finishes
  unsigned short* xh  = (unsigned short*)tail;
  unsigned short* xl  = xh + (size_t)SLEN * DIN;
  unsigned short* Wth = xl + (size_t)SLEN * DIN;
  unsigned short* Wtl = Wth + 192 * DIN;

  k_splitx<<<dim3(4096), dim3(256), 0, stream>>>(x, xh, xl);
  k_splitw<<<dim3(384), dim3(256), 0, stream>>>(Wq, Wk, Wv, Wth, Wtl);
  k_qkv<<<dim3(512), dim3(256), 0, stream>>>(xh, xl, Wth, Wtl, Qh, Ql, Kh, Kl, Vt);

  // stage-2 overlay of tail: pML + pOn (17.8 MB for NS=16)
  auto need = [&](int ns) {
    size_t stage2 = (size_t)ns * SLEN * 8 + (size_t)ns * SLEN * 64 * 2;
    size_t stage1 = (size_t)2 * SLEN * DIN * 2 + (size_t)2 * 192 * DIN * 2;
    return 5 * QB + (stage2 > stage1 ? stage2 : stage1);
  };
#define RUN_NS(NSV)                                                                     \
  {                                                                                     \
    float* pML = (float*)tail;                                                          \
    unsigned short* pOn = (unsigned short*)(tail + (size_t)NSV * SLEN * 8);             \
    k_flash<NSV><<<dim3(32, NSV), dim3(256), 0, stream>>>(Qh, Ql, Kh, Kl, Vt, pOn, pML); \
    k_merge<NSV><<<dim3(1024), dim3(256), 0, stream>>>(pOn, pML, out);                  \
  }
  if (ws_size >= need(16))     RUN_NS(16)
  else                         RUN_NS(8)
#undef RUN_NS
}

// Round 14
// 97.963 us; speedup vs baseline: 1.0561x; 1.0561x over previous
//
#include <hip/hip_runtime.h>

#define SLEN 8192
#define DIN  512

typedef short bf16x8 __attribute__((ext_vector_type(8)));
typedef float f32x4  __attribute__((ext_vector_type(4)));
typedef float f32x16 __attribute__((ext_vector_type(16)));
typedef unsigned int u32x4 __attribute__((ext_vector_type(4)));
typedef unsigned int u32x2 __attribute__((ext_vector_type(2)));

__device__ __forceinline__ unsigned short f2bf(float f) {
  unsigned int u = __float_as_uint(f);
  u += 0x7FFFu + ((u >> 16) & 1u);           // RNE
  return (unsigned short)(u >> 16);
}
__device__ __forceinline__ float bf2f(unsigned short h) {
  return __uint_as_float(((unsigned int)h) << 16);
}
__device__ __forceinline__ unsigned int cvtpk(float lo, float hi) {
  unsigned int r;
  asm volatile("v_cvt_pk_bf16_f32 %0, %1, %2" : "=v"(r) : "v"(lo), "v"(hi));
  return r;
}

#define MFMA16(a, b, c) __builtin_amdgcn_mfma_f32_16x16x32_bf16((a), (b), (c), 0, 0, 0)
#define MFMA32(a, b, c) __builtin_amdgcn_mfma_f32_32x32x16_bf16((a), (b), (c), 0, 0, 0)

// XOR swizzle for [row][128B] LDS tiles (read side; write side = pre-swizzled global src)
__device__ __forceinline__ int SW(int row, int off) {
  return row * 128 + (off ^ ((row & 7) << 4));
}

// ------- B: split + transpose W -> Wt[n][k], n: 0-63 Q(scaled), 64-127 K, 128-191 V -------
__global__ __launch_bounds__(256) void k_splitw(const float* __restrict__ Wq,
                                                const float* __restrict__ Wk,
                                                const float* __restrict__ Wv,
                                                unsigned short* __restrict__ Wth,
                                                unsigned short* __restrict__ Wtl) {
  int idx = blockIdx.x * 256 + threadIdx.x;  // n*512 + k, 98304 total
  int n = idx >> 9, k = idx & 511;
  float w;
  if (n < 64)       w = Wq[k * 64 + n] * 0.18033688011112042f;  // log2(e)/8 folded in
  else if (n < 128) w = Wk[k * 64 + (n - 64)];
  else              w = Wv[k * 64 + (n - 128)];
  unsigned short h = f2bf(w);
  Wth[idx] = h;
  Wtl[idx] = f2bf(w - bf2f(h));
}

// ---------------- C: QKV = x @ [Wq|Wk|Wv], x read ONCE, 16-row m-tiles ----------------
__global__ __launch_bounds__(256) void k_qkv(const float* __restrict__ x,
                                             const unsigned short* __restrict__ Wth,
                                             const unsigned short* __restrict__ Wtl,
                                             unsigned short* __restrict__ Qh,
                                             unsigned short* __restrict__ Ql,
                                             unsigned short* __restrict__ Kh,
                                             unsigned short* __restrict__ Kl,
                                             unsigned short* __restrict__ Vt) {
  const int tid = threadIdx.x;
  const int wave = tid >> 6, lane = tid & 63;
  const int c = lane & 15, g = lane >> 4;
  const int mbase = blockIdx.x * 16;              // 512 m-tiles of 16 rows
  const int nt0 = wave * 3;                       // each wave: 3 of 12 n-tiles

  const int rowA = mbase + c;                     // all waves share rows (L1 broadcast)
  f32x4 acc[3];
  for (int j = 0; j < 3; ++j) acc[j] = (f32x4){0.f, 0.f, 0.f, 0.f};

  for (int k0 = 0; k0 < DIN; k0 += 32) {
    const float* xp = x + (size_t)rowA * DIN + k0 + g * 8;
    float4 f0 = *reinterpret_cast<const float4*>(xp);
    float4 f1 = *reinterpret_cast<const float4*>(xp + 4);
    float fv[8] = {f0.x, f0.y, f0.z, f0.w, f1.x, f1.y, f1.z, f1.w};
    bf16x8 ah, al;
#pragma unroll
    for (int j = 0; j < 8; ++j) {
      unsigned short h = f2bf(fv[j]);
      ah[j] = (short)h;
      al[j] = (short)f2bf(fv[j] - bf2f(h));
    }
#pragma unroll
    for (int j = 0; j < 3; ++j) {
      int ncol = (nt0 + j) * 16 + c;
      bf16x8 bh = *reinterpret_cast<const bf16x8*>(&Wth[ncol * DIN + k0 + g * 8]);
      bf16x8 bl = *reinterpret_cast<const bf16x8*>(&Wtl[ncol * DIN + k0 + g * 8]);
      acc[j] = MFMA16(ah, bh, acc[j]);
      acc[j] = MFMA16(ah, bl, acc[j]);
      acc[j] = MFMA16(al, bh, acc[j]);
    }
  }
  // C layout: col=lane&15, row=(lane>>4)*4+r  (16-row tile)
#pragma unroll
  for (int j = 0; j < 3; ++j) {
    int nt = nt0 + j;
    if (nt < 8) {
#pragma unroll
      for (int r = 0; r < 4; ++r) {
        int Rrow = mbase + g * 4 + r;
        float v = acc[j][r];
        unsigned short h = f2bf(v);
        unsigned short lo = f2bf(v - bf2f(h));
        if (nt < 4) {
          Qh[Rrow * 64 + nt * 16 + c] = h;
          Ql[Rrow * 64 + nt * 16 + c] = lo;
        } else {
          Kh[Rrow * 64 + (nt - 4) * 16 + c] = h;
          Kl[Rrow * 64 + (nt - 4) * 16 + c] = lo;
        }
      }
    } else {
      int np = nt * 16 + c - 128;
      int Rbase = mbase + g * 4;
      u32x2 pk;
      pk.x = cvtpk(acc[j][0], acc[j][1]);
      pk.y = cvtpk(acc[j][2], acc[j][3]);
      *reinterpret_cast<u32x2*>(&Vt[(size_t)np * SLEN + Rbase]) = pk;  // V^T [64][8192]
    }
  }
}

// ---------------- D: flash attention, swapped 32x32, softmax||MFMA pipelined ----------------
template <int NS>
__global__ __launch_bounds__(256, 2) void k_flash(const unsigned short* __restrict__ Qh,
                                                  const unsigned short* __restrict__ Ql,
                                                  const unsigned short* __restrict__ Kh,
                                                  const unsigned short* __restrict__ Kl,
                                                  const unsigned short* __restrict__ Vt,
                                                  unsigned short* __restrict__ pOn,
                                                  float* __restrict__ pML) {
  constexpr int KIT = 128 / NS;   // 64-key tiles per split
  __shared__ __align__(16) unsigned char smem[2 * 24576];   // dbuf {KH,KL,VT}
  const int tid = threadIdx.x;
  const int wave = tid >> 6, lane = tid & 63;
  const int q32 = lane & 31, hi = lane >> 5;
  const int qtile = blockIdx.x;   // 32 q-tiles of 256
  const int ks = blockIdx.y;

  // Q B-fragments: B[k=hi*8+j][col=q32], per (qs, kk): bf16x8 of own q-row
  int qrow[2];
  bf16x8 qfh[2][4], qfl[2][4];
#pragma unroll
  for (int qs = 0; qs < 2; ++qs) {
    qrow[qs] = qtile * 256 + wave * 64 + qs * 32 + q32;
#pragma unroll
    for (int kk = 0; kk < 4; ++kk) {
      qfh[qs][kk] = *reinterpret_cast<const bf16x8*>(&Qh[qrow[qs] * 64 + kk * 16 + hi * 8]);
      qfl[qs][kk] = *reinterpret_cast<const bf16x8*>(&Ql[qrow[qs] * 64 + kk * 16 + hi * 8]);
    }
  }

  f32x16 o[2][2];
#pragma unroll
  for (int qs = 0; qs < 2; ++qs)
#pragma unroll
    for (int db = 0; db < 2; ++db)
#pragma unroll
      for (int r = 0; r < 16; ++r) o[qs][db][r] = 0.f;
  float m_run[2] = {-1e30f, -1e30f};
  float l_run[2] = {0.f, 0.f};

  // DMA staging: wave w covers chunks [w*6, w*6+6) of 24 x 1KB; lane lays its 16B at
  // base + lane*16 (HW). Global source col pre-swizzled so LDS[row][seg] = G[row][seg^(row&7)].
  const int r8 = lane >> 3;
  const int ce = ((lane & 7) ^ r8) * 8;          // source col in elems (8 bf16 = 16B)
  auto STAGE = [&](int it, int bo) {
    const int kb = ks * (SLEN / NS) + it * 64;
#pragma unroll
    for (int u = 0; u < 6; ++u) {
      int ch = wave * 6 + u;
      int arr = ch >> 3;
      int row = (ch & 7) * 8 + r8;
      const unsigned short* src;
      if (arr == 0)      src = &Kh[(kb + row) * 64 + ce];
      else if (arr == 1) src = &Kl[(kb + row) * 64 + ce];
      else               src = &Vt[(size_t)row * SLEN + kb + ce];
      __builtin_amdgcn_global_load_lds(
          (const __attribute__((address_space(1))) unsigned int*)src,
          (__attribute__((address_space(3))) unsigned int*)(smem + bo + ch * 1024),
          16, 0, 0);
    }
  };

  int boff = 0;
  STAGE(0, 0);
  __syncthreads();                                // vmcnt(0): first tile landed

  for (int it = 0; it < KIT; ++it) {
    if (it + 1 < KIT) STAGE(it + 1, boff ^ 24576);   // next tile flies during compute
    unsigned char* KH = smem + boff;
    unsigned char* KL = KH + 8192;
    unsigned char* VT = KH + 16384;

#pragma unroll
    for (int s = 0; s < 2; ++s) {          // two 32-key subtiles
      bf16x8 kfh[4], kfl[4];
#pragma unroll
      for (int kk = 0; kk < 4; ++kk) {
        kfh[kk] = *reinterpret_cast<const bf16x8*>(&KH[SW(32 * s + q32, 32 * kk + 16 * hi)]);
        kfl[kk] = *reinterpret_cast<const bf16x8*>(&KL[SW(32 * s + q32, 32 * kk + 16 * hi)]);
      }

      // ---- S0 chain (12 MFMA) ----
      f32x16 S0;
#pragma unroll
      for (int r = 0; r < 16; ++r) S0[r] = 0.f;
      __builtin_amdgcn_s_setprio(1);
#pragma unroll
      for (int kk = 0; kk < 4; ++kk) {
        S0 = MFMA32(kfh[kk], qfh[0][kk], S0);
        S0 = MFMA32(kfh[kk], qfl[0][kk], S0);
        S0 = MFMA32(kfl[kk], qfh[0][kk], S0);
      }
      // ---- S1 chain issued BEFORE sm0: sm0 VALU/trans hides under S1's MFMA window ----
      f32x16 S1;
#pragma unroll
      for (int r = 0; r < 16; ++r) S1[r] = 0.f;
#pragma unroll
      for (int kk = 0; kk < 4; ++kk) {
        S1 = MFMA32(kfh[kk], qfh[1][kk], S1);
        S1 = MFMA32(kfh[kk], qfl[1][kk], S1);
        S1 = MFMA32(kfl[kk], qfh[1][kk], S1);
      }
      __builtin_amdgcn_s_setprio(0);

      // ---- sm0 (overlaps S1 in-flight) ----
      bf16x8 pb0a, pb0b;
      float ls0;
      {
        float pm = S0[0];
#pragma unroll
        for (int r = 1; r < 16; ++r) pm = fmaxf(pm, S0[r]);
        pm = fmaxf(pm, __shfl_xor(pm, 32));
        if (!__all(pm - m_run[0] <= 8.0f)) {
          float mnew = fmaxf(m_run[0], pm);
          float alpha = exp2f(m_run[0] - mnew);
#pragma unroll
          for (int db = 0; db < 2; ++db)
#pragma unroll
            for (int r = 0; r < 16; ++r) o[0][db][r] *= alpha;
          l_run[0] *= alpha;
          m_run[0] = mnew;
        }
        float p[16];
#pragma unroll
        for (int r = 0; r < 16; ++r) p[r] = exp2f(S0[r] - m_run[0]);
        // VALU rowsum (R12-proven): lane tree + cross-half shfl
        float t0s = (p[0] + p[1]) + (p[2] + p[3]);
        float t1s = (p[4] + p[5]) + (p[6] + p[7]);
        float t2s = (p[8] + p[9]) + (p[10] + p[11]);
        float t3s = (p[12] + p[13]) + (p[14] + p[15]);
        ls0 = (t0s + t1s) + (t2s + t3s);
        ls0 += __shfl_xor(ls0, 32);
        unsigned int W[8];
#pragma unroll
        for (int i = 0; i < 8; ++i) W[i] = cvtpk(p[2 * i], p[2 * i + 1]);
        asm volatile("v_permlane32_swap_b32 %0, %1" : "+v"(W[0]), "+v"(W[2]));
        asm volatile("v_permlane32_swap_b32 %0, %1" : "+v"(W[1]), "+v"(W[3]));
        asm volatile("v_permlane32_swap_b32 %0, %1" : "+v"(W[4]), "+v"(W[6]));
        asm volatile("v_permlane32_swap_b32 %0, %1" : "+v"(W[5]), "+v"(W[7]));
        u32x4 pw0 = {W[0], W[1], W[2], W[3]};
        u32x4 pw1 = {W[4], W[5], W[6], W[7]};
        pb0a = *reinterpret_cast<bf16x8*>(&pw0);
        pb0b = *reinterpret_cast<bf16x8*>(&pw1);
      }
      l_run[0] += ls0;

      // ---- vf loads (deferred: off the sm0 register peak) ----
      bf16x8 vf[2][2];
#pragma unroll
      for (int db = 0; db < 2; ++db)
#pragma unroll
        for (int ch = 0; ch < 2; ++ch)
          vf[db][ch] = *reinterpret_cast<const bf16x8*>(&VT[SW(32 * db + q32, 64 * s + 32 * ch + 16 * hi)]);

      // ---- PV0 issued; sm1 VALU overlaps it ----
      __builtin_amdgcn_s_setprio(1);
      o[0][0] = MFMA32(vf[0][0], pb0a, o[0][0]);
      o[0][1] = MFMA32(vf[1][0], pb0a, o[0][1]);
      o[0][0] = MFMA32(vf[0][1], pb0b, o[0][0]);
      o[0][1] = MFMA32(vf[1][1], pb0b, o[0][1]);
      __builtin_amdgcn_s_setprio(0);

      // ---- sm1 ----
      bf16x8 pb1a, pb1b;
      float ls1;
      {
        float pm = S1[0];
#pragma unroll
        for (int r = 1; r < 16; ++r) pm = fmaxf(pm, S1[r]);
        pm = fmaxf(pm, __shfl_xor(pm, 32));
        if (!__all(pm - m_run[1] <= 8.0f)) {
          float mnew = fmaxf(m_run[1], pm);
          float alpha = exp2f(m_run[1] - mnew);
#pragma unroll
          for (int db = 0; db < 2; ++db)
#pragma unroll
            for (int r = 0; r < 16; ++r) o[1][db][r] *= alpha;
          l_run[1] *= alpha;
          m_run[1] = mnew;
        }
        float p[16];
#pragma unroll
        for (int r = 0; r < 16; ++r) p[r] = exp2f(S1[r] - m_run[1]);
        float t0s = (p[0] + p[1]) + (p[2] + p[3]);
        float t1s = (p[4] + p[5]) + (p[6] + p[7]);
        float t2s = (p[8] + p[9]) + (p[10] + p[11]);
        float t3s = (p[12] + p[13]) + (p[14] + p[15]);
        ls1 = (t0s + t1s) + (t2s + t3s);
        ls1 += __shfl_xor(ls1, 32);
        unsigned int W[8];
#pragma unroll
        for (int i = 0; i < 8; ++i) W[i] = cvtpk(p[2 * i], p[2 * i + 1]);
        asm volatile("v_permlane32_swap_b32 %0, %1" : "+v"(W[0]), "+v"(W[2]));
        asm volatile("v_permlane32_swap_b32 %0, %1" : "+v"(W[1]), "+v"(W[3]));
        asm volatile("v_permlane32_swap_b32 %0, %1" : "+v"(W[4]), "+v"(W[6]));
        asm volatile("v_permlane32_swap_b32 %0, %1" : "+v"(W[5]), "+v"(W[7]));
        u32x4 pw0 = {W[0], W[1], W[2], W[3]};
        u32x4 pw1 = {W[4], W[5], W[6], W[7]};
        pb1a = *reinterpret_cast<bf16x8*>(&pw0);
        pb1b = *reinterpret_cast<bf16x8*>(&pw1);
      }
      l_run[1] += ls1;

      // ---- PV1 (next s-iter's K-frag ds_reads + S0 can overlap this) ----
      __builtin_amdgcn_s_setprio(1);
      o[1][0] = MFMA32(vf[0][0], pb1a, o[1][0]);
      o[1][1] = MFMA32(vf[1][0], pb1a, o[1][1]);
      o[1][0] = MFMA32(vf[0][1], pb1b, o[1][0]);
      o[1][1] = MFMA32(vf[1][1], pb1b, o[1][1]);
      __builtin_amdgcn_s_setprio(0);
    }
    __syncthreads();     // vmcnt(0)+lgkmcnt(0)+barrier: next tile landed, cur buffer free
    boff ^= 24576;
  }

  // epilogue: normalized bf16 partials + (m,l)
#pragma unroll
  for (int qs = 0; qs < 2; ++qs) {
    float inv = 1.0f / l_run[qs];
#pragma unroll
    for (int db = 0; db < 2; ++db)
#pragma unroll
      for (int i = 0; i < 8; ++i) {
        unsigned int w = cvtpk(o[qs][db][2 * i] * inv, o[qs][db][2 * i + 1] * inv);
        int d = 2 * (i & 1) + 8 * (i >> 1) + 4 * hi + 32 * db;
        *reinterpret_cast<unsigned int*>(&pOn[((size_t)ks * SLEN + qrow[qs]) * 64 + d]) = w;
      }
    if (hi == 0) {
      pML[((size_t)ks * SLEN + qrow[qs]) * 2 + 0] = m_run[qs];
      pML[((size_t)ks * SLEN + qrow[qs]) * 2 + 1] = l_run[qs];
    }
  }
}

// ---------------- E: merge K-split partials (u32-pair vectorized) ----------------
template <int NS>
__global__ __launch_bounds__(256) void k_merge(const unsigned short* __restrict__ pOn,
                                               const float* __restrict__ pML,
                                               float* __restrict__ out) {
  int idx = blockIdx.x * 256 + threadIdx.x;  // 262144 u32-pairs
  int row = idx >> 5, dp = idx & 31;
  float ms[NS], ls[NS];
  float M = -1e30f;
#pragma unroll
  for (int s = 0; s < NS; ++s) {
    ms[s] = pML[((size_t)s * SLEN + row) * 2 + 0];
    ls[s] = pML[((size_t)s * SLEN + row) * 2 + 1];
    M = fmaxf(M, ms[s]);
  }
  float Wsum = 0.f, O0 = 0.f, O1 = 0.f;
  const unsigned int* pOn32 = reinterpret_cast<const unsigned int*>(pOn);
#pragma unroll
  for (int s = 0; s < NS; ++s) {
    float w = ls[s] * exp2f(ms[s] - M);
    unsigned int v = pOn32[((size_t)s * SLEN + row) * 32 + dp];
    O0 += w * bf2f((unsigned short)(v & 0xFFFF));
    O1 += w * bf2f((unsigned short)(v >> 16));
    Wsum += w;
  }
  float inv = 1.0f / Wsum;
  float2 res = {O0 * inv, O1 * inv};
  *reinterpret_cast<float2*>(&out[(size_t)row * 64 + dp * 2]) = res;
}

extern "C" void kernel_launch(void* const* d_in, const int* in_sizes, int n_in,
                              void* d_out, int out_size, void* d_ws, size_t ws_size,
                              hipStream_t stream) {
  const float* x  = (const float*)d_in[0];
  const float* Wq = (const float*)d_in[1];
  const float* Wk = (const float*)d_in[2];
  const float* Wv = (const float*)d_in[3];
  float* out = (float*)d_out;

  char* w = (char*)d_ws;
  const size_t QB = (size_t)SLEN * 64 * 2;       // 1,048,576 per buffer
  unsigned short* Qh = (unsigned short*)w;
  unsigned short* Ql = Qh + SLEN * 64;
  unsigned short* Kh = Ql + SLEN * 64;
  unsigned short* Kl = Kh + SLEN * 64;
  unsigned short* Vt = Kl + SLEN * 64;
  char* tail = w + 5 * QB;                       // 5,242,880
  // W lives in [tail, tail+393216): dead once k_qkv finishes; pML/pOn overlay it later
  unsigned short* Wth = (unsigned short*)tail;
  unsigned short* Wtl = Wth + 192 * DIN;

  k_splitw<<<dim3(384), dim3(256), 0, stream>>>(Wq, Wk, Wv, Wth, Wtl);
  k_qkv<<<dim3(512), dim3(256), 0, stream>>>(x, Wth, Wtl, Qh, Ql, Kh, Kl, Vt);

  auto need = [&](int ns) {
    return 5 * QB + (size_t)ns * SLEN * 8 + (size_t)ns * SLEN * 64 * 2;
  };
#define RUN_NS(NSV)                                                                     \
  {                                                                                     \
    float* pML = (float*)tail;                                                          \
    unsigned short* pOn = (unsigned short*)(tail + (size_t)NSV * SLEN * 8);             \
    k_flash<NSV><<<dim3(32, NSV), dim3(256), 0, stream>>>(Qh, Ql, Kh, Kl, Vt, pOn, pML); \
    k_merge<NSV><<<dim3(1024), dim3(256), 0, stream>>>(pOn, pML, out);                  \
  }
  if (ws_size >= need(16))     RUN_NS(16)
  else                         RUN_NS(8)
#undef RUN_NS
}

// Round 15
// 79.637 us; speedup vs baseline: 1.2991x; 1.2301x over previous
//
#include <hip/hip_runtime.h>

#define SLEN 8192
#define DIN  512

typedef short bf16x8 __attribute__((ext_vector_type(8)));
typedef float f32x4  __attribute__((ext_vector_type(4)));
typedef float f32x16 __attribute__((ext_vector_type(16)));
typedef unsigned int u32x4 __attribute__((ext_vector_type(4)));
typedef unsigned int u32x2 __attribute__((ext_vector_type(2)));

__device__ __forceinline__ unsigned short f2bf(float f) {
  unsigned int u = __float_as_uint(f);
  u += 0x7FFFu + ((u >> 16) & 1u);           // RNE
  return (unsigned short)(u >> 16);
}
__device__ __forceinline__ float bf2f(unsigned short h) {
  return __uint_as_float(((unsigned int)h) << 16);
}
__device__ __forceinline__ unsigned int cvtpk(float lo, float hi) {
  unsigned int r;
  asm volatile("v_cvt_pk_bf16_f32 %0, %1, %2" : "=v"(r) : "v"(lo), "v"(hi));
  return r;
}

#define MFMA16(a, b, c) __builtin_amdgcn_mfma_f32_16x16x32_bf16((a), (b), (c), 0, 0, 0)
#define MFMA32(a, b, c) __builtin_amdgcn_mfma_f32_32x32x16_bf16((a), (b), (c), 0, 0, 0)

// XOR swizzle for [row][128B] LDS tiles (read side; write side = pre-swizzled global src)
__device__ __forceinline__ int SW(int row, int off) {
  return row * 128 + (off ^ ((row & 7) << 4));
}

// ------- B: split + transpose W into fragment-major layout ----------------
// Wf[(nt*16 + k0/32)*64 + lane]*8 + j  holds W[k=k0+ (lane>>4)*8 + j][n = nt*16 + (lane&15)]
// (n: 0-63 Q scaled by log2e/8, 64-127 K, 128-191 V). Wave B-fragment load = contiguous 1KB.
__global__ __launch_bounds__(256) void k_splitw(const float* __restrict__ Wq,
                                                const float* __restrict__ Wk,
                                                const float* __restrict__ Wv,
                                                unsigned short* __restrict__ Wfh,
                                                unsigned short* __restrict__ Wfl) {
  int idx = blockIdx.x * 256 + threadIdx.x;  // dst element, 98304 total
  int j = idx & 7;
  int lane = (idx >> 3) & 63;
  int chunk = idx >> 9;                      // 0..191
  int kk = chunk & 15;                       // k0/32
  int nt = chunk >> 4;                       // 0..11
  int c = lane & 15, g = lane >> 4;
  int n = nt * 16 + c;
  int k = kk * 32 + g * 8 + j;
  float w;
  if (n < 64)       w = Wq[k * 64 + n] * 0.18033688011112042f;  // log2(e)/8 folded in
  else if (n < 128) w = Wk[k * 64 + (n - 64)];
  else              w = Wv[k * 64 + (n - 128)];
  unsigned short h = f2bf(w);
  Wfh[idx] = h;
  Wfl[idx] = f2bf(w - bf2f(h));
}

// ---------------- C: QKV = x @ [Wq|Wk|Wv], LDS-staged x, coalesced W fragments ----------------
__global__ __launch_bounds__(256) void k_qkv(const float* __restrict__ x,
                                             const unsigned short* __restrict__ Wfh,
                                             const unsigned short* __restrict__ Wfl,
                                             unsigned short* __restrict__ Qh,
                                             unsigned short* __restrict__ Ql,
                                             unsigned short* __restrict__ Kh,
                                             unsigned short* __restrict__ Kl,
                                             unsigned short* __restrict__ Vt) {
  __shared__ float4 xs4[16 * 128];                // 32 KB x-tile, f4-swizzled
  const int tid = threadIdx.x;
  const int wave = tid >> 6, lane = tid & 63;
  const int c = lane & 15, g = lane >> 4;
  const int mbase = blockIdx.x * 16;              // 512 m-tiles of 16 rows
  const int nt0 = wave * 3;                       // each wave: 3 of 12 n-tiles

  // coalesced stage: consecutive lanes read consecutive 16B within a row
#pragma unroll
  for (int p = 0; p < 8; ++p) {
    int idx = p * 256 + tid;                      // 2048 float4s
    int row = idx >> 7, c4 = idx & 127;
    xs4[row * 128 + (c4 ^ (row & 7))] =
        *reinterpret_cast<const float4*>(&x[(size_t)(mbase + row) * DIN + c4 * 4]);
  }
  __syncthreads();

  f32x4 acc[3];
  for (int j = 0; j < 3; ++j) acc[j] = (f32x4){0.f, 0.f, 0.f, 0.f};

  for (int k0 = 0; k0 < DIN; k0 += 32) {
    int c4a = (k0 >> 2) + 2 * g;
    float4 f0 = xs4[c * 128 + (c4a ^ (c & 7))];
    float4 f1 = xs4[c * 128 + ((c4a + 1) ^ (c & 7))];
    float fv[8] = {f0.x, f0.y, f0.z, f0.w, f1.x, f1.y, f1.z, f1.w};
    bf16x8 ah, al;
#pragma unroll
    for (int j = 0; j < 8; ++j) {
      unsigned short h = f2bf(fv[j]);
      ah[j] = (short)h;
      al[j] = (short)f2bf(fv[j] - bf2f(h));
    }
    const int kidx = k0 >> 5;
#pragma unroll
    for (int j = 0; j < 3; ++j) {
      int nt = nt0 + j;
      size_t base = ((size_t)(nt * 16 + kidx) * 64 + lane) * 8;
      bf16x8 bh = *reinterpret_cast<const bf16x8*>(&Wfh[base]);
      bf16x8 bl = *reinterpret_cast<const bf16x8*>(&Wfl[base]);
      acc[j] = MFMA16(ah, bh, acc[j]);
      acc[j] = MFMA16(ah, bl, acc[j]);
      acc[j] = MFMA16(al, bh, acc[j]);
    }
  }
  // C layout: col=lane&15, row=(lane>>4)*4+r  (16-row tile)
#pragma unroll
  for (int j = 0; j < 3; ++j) {
    int nt = nt0 + j;
    if (nt < 8) {
#pragma unroll
      for (int r = 0; r < 4; ++r) {
        int Rrow = mbase + g * 4 + r;
        float v = acc[j][r];
        unsigned short h = f2bf(v);
        unsigned short lo = f2bf(v - bf2f(h));
        if (nt < 4) {
          Qh[Rrow * 64 + nt * 16 + c] = h;
          Ql[Rrow * 64 + nt * 16 + c] = lo;
        } else {
          Kh[Rrow * 64 + (nt - 4) * 16 + c] = h;
          Kl[Rrow * 64 + (nt - 4) * 16 + c] = lo;
        }
      }
    } else {
      int np = nt * 16 + c - 128;
      int Rbase = mbase + g * 4;
      u32x2 pk;
      pk.x = cvtpk(acc[j][0], acc[j][1]);
      pk.y = cvtpk(acc[j][2], acc[j][3]);
      *reinterpret_cast<u32x2*>(&Vt[(size_t)np * SLEN + Rbase]) = pk;  // V^T [64][8192]
    }
  }
}

// ---------------- D: flash attention, swapped 32x32, softmax||MFMA pipelined ----------------
template <int NS>
__global__ __launch_bounds__(256, 2) void k_flash(const unsigned short* __restrict__ Qh,
                                                  const unsigned short* __restrict__ Ql,
                                                  const unsigned short* __restrict__ Kh,
                                                  const unsigned short* __restrict__ Kl,
                                                  const unsigned short* __restrict__ Vt,
                                                  unsigned short* __restrict__ pOn,
                                                  float* __restrict__ pML) {
  constexpr int KIT = 128 / NS;   // 64-key tiles per split
  __shared__ __align__(16) unsigned char smem[2 * 24576];   // dbuf {KH,KL,VT}
  const int tid = threadIdx.x;
  const int wave = tid >> 6, lane = tid & 63;
  const int q32 = lane & 31, hi = lane >> 5;
  const int qtile = blockIdx.x;   // 32 q-tiles of 256
  const int ks = blockIdx.y;

  // Q B-fragments: B[k=hi*8+j][col=q32], per (qs, kk): bf16x8 of own q-row
  int qrow[2];
  bf16x8 qfh[2][4], qfl[2][4];
#pragma unroll
  for (int qs = 0; qs < 2; ++qs) {
    qrow[qs] = qtile * 256 + wave * 64 + qs * 32 + q32;
#pragma unroll
    for (int kk = 0; kk < 4; ++kk) {
      qfh[qs][kk] = *reinterpret_cast<const bf16x8*>(&Qh[qrow[qs] * 64 + kk * 16 + hi * 8]);
      qfl[qs][kk] = *reinterpret_cast<const bf16x8*>(&Ql[qrow[qs] * 64 + kk * 16 + hi * 8]);
    }
  }

  f32x16 o[2][2];
#pragma unroll
  for (int qs = 0; qs < 2; ++qs)
#pragma unroll
    for (int db = 0; db < 2; ++db)
#pragma unroll
      for (int r = 0; r < 16; ++r) o[qs][db][r] = 0.f;
  float m_run[2] = {-1e30f, -1e30f};
  float l_run[2] = {0.f, 0.f};

  // DMA staging: wave w covers chunks [w*6, w*6+6) of 24 x 1KB; lane lays its 16B at
  // base + lane*16 (HW). Global source col pre-swizzled so LDS[row][seg] = G[row][seg^(row&7)].
  const int r8 = lane >> 3;
  const int ce = ((lane & 7) ^ r8) * 8;          // source col in elems (8 bf16 = 16B)
  auto STAGE = [&](int it, int bo) {
    const int kb = ks * (SLEN / NS) + it * 64;
#pragma unroll
    for (int u = 0; u < 6; ++u) {
      int ch = wave * 6 + u;
      int arr = ch >> 3;
      int row = (ch & 7) * 8 + r8;
      const unsigned short* src;
      if (arr == 0)      src = &Kh[(kb + row) * 64 + ce];
      else if (arr == 1) src = &Kl[(kb + row) * 64 + ce];
      else               src = &Vt[(size_t)row * SLEN + kb + ce];
      __builtin_amdgcn_global_load_lds(
          (const __attribute__((address_space(1))) unsigned int*)src,
          (__attribute__((address_space(3))) unsigned int*)(smem + bo + ch * 1024),
          16, 0, 0);
    }
  };

  int boff = 0;
  STAGE(0, 0);
  __syncthreads();                                // vmcnt(0): first tile landed

  for (int it = 0; it < KIT; ++it) {
    if (it + 1 < KIT) STAGE(it + 1, boff ^ 24576);   // next tile flies during compute
    unsigned char* KH = smem + boff;
    unsigned char* KL = KH + 8192;
    unsigned char* VT = KH + 16384;

#pragma unroll
    for (int s = 0; s < 2; ++s) {          // two 32-key subtiles
      bf16x8 kfh[4], kfl[4];
#pragma unroll
      for (int kk = 0; kk < 4; ++kk) {
        kfh[kk] = *reinterpret_cast<const bf16x8*>(&KH[SW(32 * s + q32, 32 * kk + 16 * hi)]);
        kfl[kk] = *reinterpret_cast<const bf16x8*>(&KL[SW(32 * s + q32, 32 * kk + 16 * hi)]);
      }

      // ---- S0 chain (12 MFMA) ----
      f32x16 S0;
#pragma unroll
      for (int r = 0; r < 16; ++r) S0[r] = 0.f;
      __builtin_amdgcn_s_setprio(1);
#pragma unroll
      for (int kk = 0; kk < 4; ++kk) {
        S0 = MFMA32(kfh[kk], qfh[0][kk], S0);
        S0 = MFMA32(kfh[kk], qfl[0][kk], S0);
        S0 = MFMA32(kfl[kk], qfh[0][kk], S0);
      }
      // ---- S1 chain issued BEFORE sm0: sm0 VALU/trans hides under S1's MFMA window ----
      f32x16 S1;
#pragma unroll
      for (int r = 0; r < 16; ++r) S1[r] = 0.f;
#pragma unroll
      for (int kk = 0; kk < 4; ++kk) {
        S1 = MFMA32(kfh[kk], qfh[1][kk], S1);
        S1 = MFMA32(kfh[kk], qfl[1][kk], S1);
        S1 = MFMA32(kfl[kk], qfh[1][kk], S1);
      }
      __builtin_amdgcn_s_setprio(0);

      // ---- sm0 (overlaps S1 in-flight) ----
      bf16x8 pb0a, pb0b;
      float ls0;
      {
        float pm = S0[0];
#pragma unroll
        for (int r = 1; r < 16; ++r) pm = fmaxf(pm, S0[r]);
        pm = fmaxf(pm, __shfl_xor(pm, 32));
        if (!__all(pm - m_run[0] <= 8.0f)) {
          float mnew = fmaxf(m_run[0], pm);
          float alpha = exp2f(m_run[0] - mnew);
#pragma unroll
          for (int db = 0; db < 2; ++db)
#pragma unroll
            for (int r = 0; r < 16; ++r) o[0][db][r] *= alpha;
          l_run[0] *= alpha;
          m_run[0] = mnew;
        }
        float p[16];
#pragma unroll
        for (int r = 0; r < 16; ++r) p[r] = exp2f(S0[r] - m_run[0]);
        // VALU rowsum (R12-proven): lane tree + cross-half shfl
        float t0s = (p[0] + p[1]) + (p[2] + p[3]);
        float t1s = (p[4] + p[5]) + (p[6] + p[7]);
        float t2s = (p[8] + p[9]) + (p[10] + p[11]);
        float t3s = (p[12] + p[13]) + (p[14] + p[15]);
        ls0 = (t0s + t1s) + (t2s + t3s);
        ls0 += __shfl_xor(ls0, 32);
        unsigned int W[8];
#pragma unroll
        for (int i = 0; i < 8; ++i) W[i] = cvtpk(p[2 * i], p[2 * i + 1]);
        asm volatile("v_permlane32_swap_b32 %0, %1" : "+v"(W[0]), "+v"(W[2]));
        asm volatile("v_permlane32_swap_b32 %0, %1" : "+v"(W[1]), "+v"(W[3]));
        asm volatile("v_permlane32_swap_b32 %0, %1" : "+v"(W[4]), "+v"(W[6]));
        asm volatile("v_permlane32_swap_b32 %0, %1" : "+v"(W[5]), "+v"(W[7]));
        u32x4 pw0 = {W[0], W[1], W[2], W[3]};
        u32x4 pw1 = {W[4], W[5], W[6], W[7]};
        pb0a = *reinterpret_cast<bf16x8*>(&pw0);
        pb0b = *reinterpret_cast<bf16x8*>(&pw1);
      }
      l_run[0] += ls0;

      // ---- vf loads (deferred: off the sm0 register peak) ----
      bf16x8 vf[2][2];
#pragma unroll
      for (int db = 0; db < 2; ++db)
#pragma unroll
        for (int ch = 0; ch < 2; ++ch)
          vf[db][ch] = *reinterpret_cast<const bf16x8*>(&VT[SW(32 * db + q32, 64 * s + 32 * ch + 16 * hi)]);

      // ---- PV0 issued; sm1 VALU overlaps it ----
      __builtin_amdgcn_s_setprio(1);
      o[0][0] = MFMA32(vf[0][0], pb0a, o[0][0]);
      o[0][1] = MFMA32(vf[1][0], pb0a, o[0][1]);
      o[0][0] = MFMA32(vf[0][1], pb0b, o[0][0]);
      o[0][1] = MFMA32(vf[1][1], pb0b, o[0][1]);
      __builtin_amdgcn_s_setprio(0);

      // ---- sm1 ----
      bf16x8 pb1a, pb1b;
      float ls1;
      {
        float pm = S1[0];
#pragma unroll
        for (int r = 1; r < 16; ++r) pm = fmaxf(pm, S1[r]);
        pm = fmaxf(pm, __shfl_xor(pm, 32));
        if (!__all(pm - m_run[1] <= 8.0f)) {
          float mnew = fmaxf(m_run[1], pm);
          float alpha = exp2f(m_run[1] - mnew);
#pragma unroll
          for (int db = 0; db < 2; ++db)
#pragma unroll
            for (int r = 0; r < 16; ++r) o[1][db][r] *= alpha;
          l_run[1] *= alpha;
          m_run[1] = mnew;
        }
        float p[16];
#pragma unroll
        for (int r = 0; r < 16; ++r) p[r] = exp2f(S1[r] - m_run[1]);
        float t0s = (p[0] + p[1]) + (p[2] + p[3]);
        float t1s = (p[4] + p[5]) + (p[6] + p[7]);
        float t2s = (p[8] + p[9]) + (p[10] + p[11]);
        float t3s = (p[12] + p[13]) + (p[14] + p[15]);
        ls1 = (t0s + t1s) + (t2s + t3s);
        ls1 += __shfl_xor(ls1, 32);
        unsigned int W[8];
#pragma unroll
        for (int i = 0; i < 8; ++i) W[i] = cvtpk(p[2 * i], p[2 * i + 1]);
        asm volatile("v_permlane32_swap_b32 %0, %1" : "+v"(W[0]), "+v"(W[2]));
        asm volatile("v_permlane32_swap_b32 %0, %1" : "+v"(W[1]), "+v"(W[3]));
        asm volatile("v_permlane32_swap_b32 %0, %1" : "+v"(W[4]), "+v"(W[6]));
        asm volatile("v_permlane32_swap_b32 %0, %1" : "+v"(W[5]), "+v"(W[7]));
        u32x4 pw0 = {W[0], W[1], W[2], W[3]};
        u32x4 pw1 = {W[4], W[5], W[6], W[7]};
        pb1a = *reinterpret_cast<bf16x8*>(&pw0);
        pb1b = *reinterpret_cast<bf16x8*>(&pw1);
      }
      l_run[1] += ls1;

      // ---- PV1 (next s-iter's K-frag ds_reads + S0 can overlap this) ----
      __builtin_amdgcn_s_setprio(1);
      o[1][0] = MFMA32(vf[0][0], pb1a, o[1][0]);
      o[1][1] = MFMA32(vf[1][0], pb1a, o[1][1]);
      o[1][0] = MFMA32(vf[0][1], pb1b, o[1][0]);
      o[1][1] = MFMA32(vf[1][1], pb1b, o[1][1]);
      __builtin_amdgcn_s_setprio(0);
    }
    __syncthreads();     // vmcnt(0)+lgkmcnt(0)+barrier: next tile landed, cur buffer free
    boff ^= 24576;
  }

  // epilogue: normalized bf16 partials + (m,l)
#pragma unroll
  for (int qs = 0; qs < 2; ++qs) {
    float inv = 1.0f / l_run[qs];
#pragma unroll
    for (int db = 0; db < 2; ++db)
#pragma unroll
      for (int i = 0; i < 8; ++i) {
        unsigned int w = cvtpk(o[qs][db][2 * i] * inv, o[qs][db][2 * i + 1] * inv);
        int d = 2 * (i & 1) + 8 * (i >> 1) + 4 * hi + 32 * db;
        *reinterpret_cast<unsigned int*>(&pOn[((size_t)ks * SLEN + qrow[qs]) * 64 + d]) = w;
      }
    if (hi == 0) {
      pML[((size_t)ks * SLEN + qrow[qs]) * 2 + 0] = m_run[qs];
      pML[((size_t)ks * SLEN + qrow[qs]) * 2 + 1] = l_run[qs];
    }
  }
}

// ---------------- E: merge K-split partials (u32-pair vectorized) ----------------
template <int NS>
__global__ __launch_bounds__(256) void k_merge(const unsigned short* __restrict__ pOn,
                                               const float* __restrict__ pML,
                                               float* __restrict__ out) {
  int idx = blockIdx.x * 256 + threadIdx.x;  // 262144 u32-pairs
  int row = idx >> 5, dp = idx & 31;
  float ms[NS], ls[NS];
  float M = -1e30f;
#pragma unroll
  for (int s = 0; s < NS; ++s) {
    ms[s] = pML[((size_t)s * SLEN + row) * 2 + 0];
    ls[s] = pML[((size_t)s * SLEN + row) * 2 + 1];
    M = fmaxf(M, ms[s]);
  }
  float Wsum = 0.f, O0 = 0.f, O1 = 0.f;
  const unsigned int* pOn32 = reinterpret_cast<const unsigned int*>(pOn);
#pragma unroll
  for (int s = 0; s < NS; ++s) {
    float w = ls[s] * exp2f(ms[s] - M);
    unsigned int v = pOn32[((size_t)s * SLEN + row) * 32 + dp];
    O0 += w * bf2f((unsigned short)(v & 0xFFFF));
    O1 += w * bf2f((unsigned short)(v >> 16));
    Wsum += w;
  }
  float inv = 1.0f / Wsum;
  float2 res = {O0 * inv, O1 * inv};
  *reinterpret_cast<float2*>(&out[(size_t)row * 64 + dp * 2]) = res;
}

extern "C" void kernel_launch(void* const* d_in, const int* in_sizes, int n_in,
                              void* d_out, int out_size, void* d_ws, size_t ws_size,
                              hipStream_t stream) {
  const float* x  = (const float*)d_in[0];
  const float* Wq = (const float*)d_in[1];
  const float* Wk = (const float*)d_in[2];
  const float* Wv = (const float*)d_in[3];
  float* out = (float*)d_out;

  char* w = (char*)d_ws;
  const size_t QB = (size_t)SLEN * 64 * 2;       // 1,048,576 per buffer
  unsigned short* Qh = (unsigned short*)w;
  unsigned short* Ql = Qh + SLEN * 64;
  unsigned short* Kh = Ql + SLEN * 64;
  unsigned short* Kl = Kh + SLEN * 64;
  unsigned short* Vt = Kl + SLEN * 64;
  char* tail = w + 5 * QB;                       // 5,242,880
  // W lives in [tail, tail+393216): dead once k_qkv finishes; pML/pOn overlay it later
  unsigned short* Wfh = (unsigned short*)tail;
  unsigned short* Wfl = Wfh + 192 * DIN;

  k_splitw<<<dim3(384), dim3(256), 0, stream>>>(Wq, Wk, Wv, Wfh, Wfl);
  k_qkv<<<dim3(512), dim3(256), 0, stream>>>(x, Wfh, Wfl, Qh, Ql, Kh, Kl, Vt);

  auto need = [&](int ns) {
    return 5 * QB + (size_t)ns * SLEN * 8 + (size_t)ns * SLEN * 64 * 2;
  };
#define RUN_NS(NSV)                                                                     \
  {                                                                                     \
    float* pML = (float*)tail;                                                          \
    unsigned short* pOn = (unsigned short*)(tail + (size_t)NSV * SLEN * 8);             \
    k_flash<NSV><<<dim3(32, NSV), dim3(256), 0, stream>>>(Qh, Ql, Kh, Kl, Vt, pOn, pML); \
    k_merge<NSV><<<dim3(1024), dim3(256), 0, stream>>>(pOn, pML, out);                  \
  }
  if (ws_size >= need(16))     RUN_NS(16)
  else                         RUN_NS(8)
#undef RUN_NS
}

// Round 16
// 79.030 us; speedup vs baseline: 1.3091x; 1.0077x over previous
//
#include <hip/hip_runtime.h>

#define SLEN 8192
#define DIN  512

typedef short bf16x8 __attribute__((ext_vector_type(8)));
typedef float f32x4  __attribute__((ext_vector_type(4)));
typedef float f32x16 __attribute__((ext_vector_type(16)));
typedef unsigned int u32x4 __attribute__((ext_vector_type(4)));
typedef unsigned int u32x2 __attribute__((ext_vector_type(2)));

__device__ __forceinline__ unsigned short f2bf(float f) {
  unsigned int u = __float_as_uint(f);
  u += 0x7FFFu + ((u >> 16) & 1u);           // RNE
  return (unsigned short)(u >> 16);
}
__device__ __forceinline__ float bf2f(unsigned short h) {
  return __uint_as_float(((unsigned int)h) << 16);
}
__device__ __forceinline__ unsigned int cvtpk(float lo, float hi) {
  unsigned int r;
  asm volatile("v_cvt_pk_bf16_f32 %0, %1, %2" : "=v"(r) : "v"(lo), "v"(hi));
  return r;
}

#define MFMA16(a, b, c) __builtin_amdgcn_mfma_f32_16x16x32_bf16((a), (b), (c), 0, 0, 0)
#define MFMA32(a, b, c) __builtin_amdgcn_mfma_f32_32x32x16_bf16((a), (b), (c), 0, 0, 0)

// XOR swizzle for [row][128B] LDS tiles (read side; write side = pre-swizzled global src)
__device__ __forceinline__ int SW(int row, int off) {
  return row * 128 + (off ^ ((row & 7) << 4));
}

// ------- B: split + transpose W into fragment-major layout ----------------
__global__ __launch_bounds__(256) void k_splitw(const float* __restrict__ Wq,
                                                const float* __restrict__ Wk,
                                                const float* __restrict__ Wv,
                                                unsigned short* __restrict__ Wfh,
                                                unsigned short* __restrict__ Wfl) {
  int idx = blockIdx.x * 256 + threadIdx.x;  // dst element, 98304 total
  int j = idx & 7;
  int lane = (idx >> 3) & 63;
  int chunk = idx >> 9;                      // 0..191
  int kk = chunk & 15;                       // k0/32
  int nt = chunk >> 4;                       // 0..11
  int c = lane & 15, g = lane >> 4;
  int n = nt * 16 + c;
  int k = kk * 32 + g * 8 + j;
  float w;
  if (n < 64)       w = Wq[k * 64 + n] * 0.18033688011112042f;  // log2(e)/8 folded in
  else if (n < 128) w = Wk[k * 64 + (n - 64)];
  else              w = Wv[k * 64 + (n - 128)];
  unsigned short h = f2bf(w);
  Wfh[idx] = h;
  Wfl[idx] = f2bf(w - bf2f(h));
}

// ---------------- C: QKV = x @ [Wq|Wk|Wv], LDS-staged x, coalesced W fragments ----------------
__global__ __launch_bounds__(256) void k_qkv(const float* __restrict__ x,
                                             const unsigned short* __restrict__ Wfh,
                                             const unsigned short* __restrict__ Wfl,
                                             unsigned short* __restrict__ Qh,
                                             unsigned short* __restrict__ Ql,
                                             unsigned short* __restrict__ Kh,
                                             unsigned short* __restrict__ Kl,
                                             unsigned short* __restrict__ Vt) {
  __shared__ float4 xs4[16 * 128];                // 32 KB x-tile, f4-swizzled
  const int tid = threadIdx.x;
  const int wave = tid >> 6, lane = tid & 63;
  const int c = lane & 15, g = lane >> 4;
  const int mbase = blockIdx.x * 16;              // 512 m-tiles of 16 rows
  const int nt0 = wave * 3;                       // each wave: 3 of 12 n-tiles

  // coalesced stage: consecutive lanes read consecutive 16B within a row
#pragma unroll
  for (int p = 0; p < 8; ++p) {
    int idx = p * 256 + tid;                      // 2048 float4s
    int row = idx >> 7, c4 = idx & 127;
    xs4[row * 128 + (c4 ^ (row & 7))] =
        *reinterpret_cast<const float4*>(&x[(size_t)(mbase + row) * DIN + c4 * 4]);
  }
  __syncthreads();

  f32x4 acc[3];
  for (int j = 0; j < 3; ++j) acc[j] = (f32x4){0.f, 0.f, 0.f, 0.f};

  for (int k0 = 0; k0 < DIN; k0 += 32) {
    int c4a = (k0 >> 2) + 2 * g;
    float4 f0 = xs4[c * 128 + (c4a ^ (c & 7))];
    float4 f1 = xs4[c * 128 + ((c4a + 1) ^ (c & 7))];
    float fv[8] = {f0.x, f0.y, f0.z, f0.w, f1.x, f1.y, f1.z, f1.w};
    bf16x8 ah, al;
#pragma unroll
    for (int j = 0; j < 8; ++j) {
      unsigned short h = f2bf(fv[j]);
      ah[j] = (short)h;
      al[j] = (short)f2bf(fv[j] - bf2f(h));
    }
    const int kidx = k0 >> 5;
#pragma unroll
    for (int j = 0; j < 3; ++j) {
      int nt = nt0 + j;
      size_t base = ((size_t)(nt * 16 + kidx) * 64 + lane) * 8;
      bf16x8 bh = *reinterpret_cast<const bf16x8*>(&Wfh[base]);
      bf16x8 bl = *reinterpret_cast<const bf16x8*>(&Wfl[base]);
      acc[j] = MFMA16(ah, bh, acc[j]);
      acc[j] = MFMA16(ah, bl, acc[j]);
      acc[j] = MFMA16(al, bh, acc[j]);
    }
  }
  // C layout: col=lane&15, row=(lane>>4)*4+r  (16-row tile)
#pragma unroll
  for (int j = 0; j < 3; ++j) {
    int nt = nt0 + j;
    if (nt < 8) {
#pragma unroll
      for (int r = 0; r < 4; ++r) {
        int Rrow = mbase + g * 4 + r;
        float v = acc[j][r];
        unsigned short h = f2bf(v);
        unsigned short lo = f2bf(v - bf2f(h));
        if (nt < 4) {
          Qh[Rrow * 64 + nt * 16 + c] = h;
          Ql[Rrow * 64 + nt * 16 + c] = lo;
        } else {
          Kh[Rrow * 64 + (nt - 4) * 16 + c] = h;
          Kl[Rrow * 64 + (nt - 4) * 16 + c] = lo;
        }
      }
    } else {
      int np = nt * 16 + c - 128;
      int Rbase = mbase + g * 4;
      u32x2 pk;
      pk.x = cvtpk(acc[j][0], acc[j][1]);
      pk.y = cvtpk(acc[j][2], acc[j][3]);
      *reinterpret_cast<u32x2*>(&Vt[(size_t)np * SLEN + Rbase]) = pk;  // V^T [64][8192]
    }
  }
}

// ---------------- D: flash attention, swapped 32x32, softmax||MFMA pipelined ----------------
template <int NS>
__global__ __launch_bounds__(256, 2) void k_flash(const unsigned short* __restrict__ Qh,
                                                  const unsigned short* __restrict__ Ql,
                                                  const unsigned short* __restrict__ Kh,
                                                  const unsigned short* __restrict__ Kl,
                                                  const unsigned short* __restrict__ Vt,
                                                  unsigned short* __restrict__ pOn,
                                                  float* __restrict__ pML) {
  constexpr int KIT = 128 / NS;   // 64-key tiles per split
  __shared__ __align__(16) unsigned char smem[2 * 24576];   // dbuf {KH,KL,VT}
  const int tid = threadIdx.x;
  const int wave = tid >> 6, lane = tid & 63;
  const int q32 = lane & 31, hi = lane >> 5;
  const int qtile = blockIdx.x;   // 32 q-tiles of 256
  const int ks = blockIdx.y;

  // Q B-fragments: B[k=hi*8+j][col=q32], per (qs, kk): bf16x8 of own q-row
  int qrow[2];
  bf16x8 qfh[2][4], qfl[2][4];
#pragma unroll
  for (int qs = 0; qs < 2; ++qs) {
    qrow[qs] = qtile * 256 + wave * 64 + qs * 32 + q32;
#pragma unroll
    for (int kk = 0; kk < 4; ++kk) {
      qfh[qs][kk] = *reinterpret_cast<const bf16x8*>(&Qh[qrow[qs] * 64 + kk * 16 + hi * 8]);
      qfl[qs][kk] = *reinterpret_cast<const bf16x8*>(&Ql[qrow[qs] * 64 + kk * 16 + hi * 8]);
    }
  }

  f32x16 o[2][2];
#pragma unroll
  for (int qs = 0; qs < 2; ++qs)
#pragma unroll
    for (int db = 0; db < 2; ++db)
#pragma unroll
      for (int r = 0; r < 16; ++r) o[qs][db][r] = 0.f;
  float m_run[2] = {-1e30f, -1e30f};
  float l_run[2] = {0.f, 0.f};

  // DMA staging: wave w covers chunks [w*6, w*6+6) of 24 x 1KB; lane lays its 16B at
  // base + lane*16 (HW). Global source col pre-swizzled so LDS[row][seg] = G[row][seg^(row&7)].
  const int r8 = lane >> 3;
  const int ce = ((lane & 7) ^ r8) * 8;          // source col in elems (8 bf16 = 16B)
  auto STAGE = [&](int it, int bo) {
    const int kb = ks * (SLEN / NS) + it * 64;
#pragma unroll
    for (int u = 0; u < 6; ++u) {
      int ch = wave * 6 + u;
      int arr = ch >> 3;
      int row = (ch & 7) * 8 + r8;
      const unsigned short* src;
      if (arr == 0)      src = &Kh[(kb + row) * 64 + ce];
      else if (arr == 1) src = &Kl[(kb + row) * 64 + ce];
      else               src = &Vt[(size_t)row * SLEN + kb + ce];
      __builtin_amdgcn_global_load_lds(
          (const __attribute__((address_space(1))) unsigned int*)src,
          (__attribute__((address_space(3))) unsigned int*)(smem + bo + ch * 1024),
          16, 0, 0);
    }
  };

  int boff = 0;
  STAGE(0, 0);
  __syncthreads();                                // vmcnt(0): first tile landed

  for (int it = 0; it < KIT; ++it) {
    if (it + 1 < KIT) STAGE(it + 1, boff ^ 24576);   // next tile flies during compute
    unsigned char* KH = smem + boff;
    unsigned char* KL = KH + 8192;
    unsigned char* VT = KH + 16384;

#pragma unroll
    for (int s = 0; s < 2; ++s) {          // two 32-key subtiles
      bf16x8 kfh[4], kfl[4];
#pragma unroll
      for (int kk = 0; kk < 4; ++kk) {
        kfh[kk] = *reinterpret_cast<const bf16x8*>(&KH[SW(32 * s + q32, 32 * kk + 16 * hi)]);
        kfl[kk] = *reinterpret_cast<const bf16x8*>(&KL[SW(32 * s + q32, 32 * kk + 16 * hi)]);
      }

      // ---- S0 chain (12 MFMA) ----
      f32x16 S0;
#pragma unroll
      for (int r = 0; r < 16; ++r) S0[r] = 0.f;
      __builtin_amdgcn_s_setprio(1);
#pragma unroll
      for (int kk = 0; kk < 4; ++kk) {
        S0 = MFMA32(kfh[kk], qfh[0][kk], S0);
        S0 = MFMA32(kfh[kk], qfl[0][kk], S0);
        S0 = MFMA32(kfl[kk], qfh[0][kk], S0);
      }
      // ---- S1 chain issued BEFORE sm0: sm0 VALU/trans hides under S1's MFMA window ----
      f32x16 S1;
#pragma unroll
      for (int r = 0; r < 16; ++r) S1[r] = 0.f;
#pragma unroll
      for (int kk = 0; kk < 4; ++kk) {
        S1 = MFMA32(kfh[kk], qfh[1][kk], S1);
        S1 = MFMA32(kfh[kk], qfl[1][kk], S1);
        S1 = MFMA32(kfl[kk], qfh[1][kk], S1);
      }
      __builtin_amdgcn_s_setprio(0);

      // ---- sm0 (overlaps S1 in-flight) ----
      bf16x8 pb0a, pb0b;
      float ls0;
      {
        // max3-shaped tree (clang fuses fmaxf(fmaxf(a,b),c) -> v_max3_f32)
        float m0 = fmaxf(fmaxf(S0[0], S0[1]), S0[2]);
        float m1 = fmaxf(fmaxf(S0[3], S0[4]), S0[5]);
        float m2 = fmaxf(fmaxf(S0[6], S0[7]), S0[8]);
        float m3 = fmaxf(fmaxf(S0[9], S0[10]), S0[11]);
        float m4 = fmaxf(fmaxf(S0[12], S0[13]), S0[14]);
        float pm = fmaxf(fmaxf(fmaxf(m0, m1), fmaxf(m2, m3)), fmaxf(m4, S0[15]));
        pm = fmaxf(pm, __shfl_xor(pm, 32));
        if (!__all(pm - m_run[0] <= 8.0f)) {
          float mnew = fmaxf(m_run[0], pm);
          float alpha = exp2f(m_run[0] - mnew);
#pragma unroll
          for (int db = 0; db < 2; ++db)
#pragma unroll
            for (int r = 0; r < 16; ++r) o[0][db][r] *= alpha;
          l_run[0] *= alpha;
          m_run[0] = mnew;
        }
        float p[16];
#pragma unroll
        for (int r = 0; r < 16; ++r) p[r] = exp2f(S0[r] - m_run[0]);
        // VALU rowsum: lane tree + cross-half shfl
        float t0s = (p[0] + p[1]) + (p[2] + p[3]);
        float t1s = (p[4] + p[5]) + (p[6] + p[7]);
        float t2s = (p[8] + p[9]) + (p[10] + p[11]);
        float t3s = (p[12] + p[13]) + (p[14] + p[15]);
        ls0 = (t0s + t1s) + (t2s + t3s);
        ls0 += __shfl_xor(ls0, 32);
        unsigned int W[8];
#pragma unroll
        for (int i = 0; i < 8; ++i) W[i] = cvtpk(p[2 * i], p[2 * i + 1]);
        asm volatile("v_permlane32_swap_b32 %0, %1" : "+v"(W[0]), "+v"(W[2]));
        asm volatile("v_permlane32_swap_b32 %0, %1" : "+v"(W[1]), "+v"(W[3]));
        asm volatile("v_permlane32_swap_b32 %0, %1" : "+v"(W[4]), "+v"(W[6]));
        asm volatile("v_permlane32_swap_b32 %0, %1" : "+v"(W[5]), "+v"(W[7]));
        u32x4 pw0 = {W[0], W[1], W[2], W[3]};
        u32x4 pw1 = {W[4], W[5], W[6], W[7]};
        pb0a = *reinterpret_cast<bf16x8*>(&pw0);
        pb0b = *reinterpret_cast<bf16x8*>(&pw1);
      }
      l_run[0] += ls0;

      // ---- vf loads (deferred: off the sm0 register peak) ----
      bf16x8 vf[2][2];
#pragma unroll
      for (int db = 0; db < 2; ++db)
#pragma unroll
        for (int ch = 0; ch < 2; ++ch)
          vf[db][ch] = *reinterpret_cast<const bf16x8*>(&VT[SW(32 * db + q32, 64 * s + 32 * ch + 16 * hi)]);

      // ---- PV0 issued; sm1 VALU overlaps it ----
      __builtin_amdgcn_s_setprio(1);
      o[0][0] = MFMA32(vf[0][0], pb0a, o[0][0]);
      o[0][1] = MFMA32(vf[1][0], pb0a, o[0][1]);
      o[0][0] = MFMA32(vf[0][1], pb0b, o[0][0]);
      o[0][1] = MFMA32(vf[1][1], pb0b, o[0][1]);
      __builtin_amdgcn_s_setprio(0);

      // ---- sm1 ----
      bf16x8 pb1a, pb1b;
      float ls1;
      {
        float m0 = fmaxf(fmaxf(S1[0], S1[1]), S1[2]);
        float m1 = fmaxf(fmaxf(S1[3], S1[4]), S1[5]);
        float m2 = fmaxf(fmaxf(S1[6], S1[7]), S1[8]);
        float m3 = fmaxf(fmaxf(S1[9], S1[10]), S1[11]);
        float m4 = fmaxf(fmaxf(S1[12], S1[13]), S1[14]);
        float pm = fmaxf(fmaxf(fmaxf(m0, m1), fmaxf(m2, m3)), fmaxf(m4, S1[15]));
        pm = fmaxf(pm, __shfl_xor(pm, 32));
        if (!__all(pm - m_run[1] <= 8.0f)) {
          float mnew = fmaxf(m_run[1], pm);
          float alpha = exp2f(m_run[1] - mnew);
#pragma unroll
          for (int db = 0; db < 2; ++db)
#pragma unroll
            for (int r = 0; r < 16; ++r) o[1][db][r] *= alpha;
          l_run[1] *= alpha;
          m_run[1] = mnew;
        }
        float p[16];
#pragma unroll
        for (int r = 0; r < 16; ++r) p[r] = exp2f(S1[r] - m_run[1]);
        float t0s = (p[0] + p[1]) + (p[2] + p[3]);
        float t1s = (p[4] + p[5]) + (p[6] + p[7]);
        float t2s = (p[8] + p[9]) + (p[10] + p[11]);
        float t3s = (p[12] + p[13]) + (p[14] + p[15]);
        ls1 = (t0s + t1s) + (t2s + t3s);
        ls1 += __shfl_xor(ls1, 32);
        unsigned int W[8];
#pragma unroll
        for (int i = 0; i < 8; ++i) W[i] = cvtpk(p[2 * i], p[2 * i + 1]);
        asm volatile("v_permlane32_swap_b32 %0, %1" : "+v"(W[0]), "+v"(W[2]));
        asm volatile("v_permlane32_swap_b32 %0, %1" : "+v"(W[1]), "+v"(W[3]));
        asm volatile("v_permlane32_swap_b32 %0, %1" : "+v"(W[4]), "+v"(W[6]));
        asm volatile("v_permlane32_swap_b32 %0, %1" : "+v"(W[5]), "+v"(W[7]));
        u32x4 pw0 = {W[0], W[1], W[2], W[3]};
        u32x4 pw1 = {W[4], W[5], W[6], W[7]};
        pb1a = *reinterpret_cast<bf16x8*>(&pw0);
        pb1b = *reinterpret_cast<bf16x8*>(&pw1);
      }
      l_run[1] += ls1;

      // ---- PV1 (next s-iter's K-frag ds_reads + S0 can overlap this) ----
      __builtin_amdgcn_s_setprio(1);
      o[1][0] = MFMA32(vf[0][0], pb1a, o[1][0]);
      o[1][1] = MFMA32(vf[1][0], pb1a, o[1][1]);
      o[1][0] = MFMA32(vf[0][1], pb1b, o[1][0]);
      o[1][1] = MFMA32(vf[1][1], pb1b, o[1][1]);
      __builtin_amdgcn_s_setprio(0);
    }
    __syncthreads();     // vmcnt(0)+lgkmcnt(0)+barrier: next tile landed, cur buffer free
    boff ^= 24576;
  }

  // epilogue: normalized bf16 partials + (m,l)
#pragma unroll
  for (int qs = 0; qs < 2; ++qs) {
    float inv = 1.0f / l_run[qs];
#pragma unroll
    for (int db = 0; db < 2; ++db)
#pragma unroll
      for (int i = 0; i < 8; ++i) {
        unsigned int w = cvtpk(o[qs][db][2 * i] * inv, o[qs][db][2 * i + 1] * inv);
        int d = 2 * (i & 1) + 8 * (i >> 1) + 4 * hi + 32 * db;
        *reinterpret_cast<unsigned int*>(&pOn[((size_t)ks * SLEN + qrow[qs]) * 64 + d]) = w;
      }
    if (hi == 0) {
      pML[((size_t)ks * SLEN + qrow[qs]) * 2 + 0] = m_run[qs];
      pML[((size_t)ks * SLEN + qrow[qs]) * 2 + 1] = l_run[qs];
    }
  }
}

// ---------------- E: merge K-split partials (u32x4 vectorized: 8 outputs/thread) ----------------
template <int NS>
__global__ __launch_bounds__(256) void k_merge(const unsigned short* __restrict__ pOn,
                                               const float* __restrict__ pML,
                                               float* __restrict__ out) {
  int idx = blockIdx.x * 256 + threadIdx.x;  // 65536 octets
  int row = idx >> 3, dq = idx & 7;
  float ms[NS], ls[NS];
  float M = -1e30f;
#pragma unroll
  for (int s = 0; s < NS; ++s) {
    ms[s] = pML[((size_t)s * SLEN + row) * 2 + 0];
    ls[s] = pML[((size_t)s * SLEN + row) * 2 + 1];
    M = fmaxf(M, ms[s]);
  }
  float Wsum = 0.f;
  float O[8] = {0.f, 0.f, 0.f, 0.f, 0.f, 0.f, 0.f, 0.f};
  const unsigned int* pOn32 = reinterpret_cast<const unsigned int*>(pOn);
#pragma unroll
  for (int s = 0; s < NS; ++s) {
    float w = ls[s] * exp2f(ms[s] - M);
    u32x4 v = *reinterpret_cast<const u32x4*>(&pOn32[((size_t)s * SLEN + row) * 32 + dq * 4]);
#pragma unroll
    for (int j = 0; j < 4; ++j) {
      O[2 * j]     += w * bf2f((unsigned short)(v[j] & 0xFFFF));
      O[2 * j + 1] += w * bf2f((unsigned short)(v[j] >> 16));
    }
    Wsum += w;
  }
  float inv = 1.0f / Wsum;
  float4 r0 = {O[0] * inv, O[1] * inv, O[2] * inv, O[3] * inv};
  float4 r1 = {O[4] * inv, O[5] * inv, O[6] * inv, O[7] * inv};
  *reinterpret_cast<float4*>(&out[(size_t)row * 64 + dq * 8]) = r0;
  *reinterpret_cast<float4*>(&out[(size_t)row * 64 + dq * 8 + 4]) = r1;
}

extern "C" void kernel_launch(void* const* d_in, const int* in_sizes, int n_in,
                              void* d_out, int out_size, void* d_ws, size_t ws_size,
                              hipStream_t stream) {
  const float* x  = (const float*)d_in[0];
  const float* Wq = (const float*)d_in[1];
  const float* Wk = (const float*)d_in[2];
  const float* Wv = (const float*)d_in[3];
  float* out = (float*)d_out;

  char* w = (char*)d_ws;
  const size_t QB = (size_t)SLEN * 64 * 2;       // 1,048,576 per buffer
  unsigned short* Qh = (unsigned short*)w;
  unsigned short* Ql = Qh + SLEN * 64;
  unsigned short* Kh = Ql + SLEN * 64;
  unsigned short* Kl = Kh + SLEN * 64;
  unsigned short* Vt = Kl + SLEN * 64;
  char* tail = w + 5 * QB;                       // 5,242,880
  // W lives in [tail, tail+393216): dead once k_qkv finishes; pML/pOn overlay it later
  unsigned short* Wfh = (unsigned short*)tail;
  unsigned short* Wfl = Wfh + 192 * DIN;

  k_splitw<<<dim3(384), dim3(256), 0, stream>>>(Wq, Wk, Wv, Wfh, Wfl);
  k_qkv<<<dim3(512), dim3(256), 0, stream>>>(x, Wfh, Wfl, Qh, Ql, Kh, Kl, Vt);

  auto need = [&](int ns) {
    return 5 * QB + (size_t)ns * SLEN * 8 + (size_t)ns * SLEN * 64 * 2;
  };
#define RUN_NS(NSV)                                                                     \
  {                                                                                     \
    float* pML = (float*)tail;                                                          \
    unsigned short* pOn = (unsigned short*)(tail + (size_t)NSV * SLEN * 8);             \
    k_flash<NSV><<<dim3(32, NSV), dim3(256), 0, stream>>>(Qh, Ql, Kh, Kl, Vt, pOn, pML); \
    k_merge<NSV><<<dim3(256), dim3(256), 0, stream>>>(pOn, pML, out);                   \
  }
  if (ws_size >= need(16))     RUN_NS(16)
  else                         RUN_NS(8)
#undef RUN_NS
}